// Round 7
// baseline (3044.544 us; speedup 1.0000x reference)
//
#include <hip/hip_runtime.h>
#include <hip/hip_bf16.h>
#include <stdint.h>

// Problem constants
constexpr int IN_F  = 4096;
constexpr int OUT_F = 4096;
constexpr int M_ROWS = 4 * 2048;   // 8192
constexpr int RANK = 16;

typedef short short8 __attribute__((ext_vector_type(8)));
typedef float f32x4 __attribute__((ext_vector_type(4)));

__device__ __forceinline__ short f2bf(float f) {
  return __builtin_bit_cast(short, __float2bfloat16(f));
}

__device__ __forceinline__ void gload16(const void* g, void* l) {
  __builtin_amdgcn_global_load_lds(
      (const __attribute__((address_space(1))) void*)g,
      (__attribute__((address_space(3))) void*)l, 16, 0, 0);
}

// ---------------------------------------------------------------------------
// Kernel 1: dequantize 4-bit weights, fold rank-16 LoRA update, emit bf16 W_eff
// ---------------------------------------------------------------------------
__global__ __launch_bounds__(256) void dequant_lora_kernel(
    const int* __restrict__ q,        // packed bytes, one byte per int32
    const float* __restrict__ wmax,
    const float* __restrict__ lut,
    const float* __restrict__ lA,     // [RANK][IN_F]
    const float* __restrict__ lB,     // [OUT_F][RANK]
    __hip_bfloat16* __restrict__ W) { // [OUT_F][IN_F]
  __shared__ float slut[16];
  if (threadIdx.x < 16) slut[threadIdx.x] = lut[threadIdx.x];
  __syncthreads();

  const int o0  = blockIdx.y * 64 + (threadIdx.x >> 5) * 8;   // 8 rows per thread
  const int ib0 = blockIdx.x * 512 + (threadIdx.x & 31) * 16; // 16 cols per thread

  #pragma unroll
  for (int h = 0; h < 2; ++h) {
    const int ib = ib0 + h * 8;
    float w[8][8];
    #pragma unroll
    for (int p = 0; p < 8; ++p) {
      const size_t l = (size_t)(o0 + p) * IN_F + ib;
      const int4 u = *(const int4*)(q + (l >> 1));   // 4 bytes -> 8 nibbles
      const float sc = wmax[l >> 6];
      w[p][0] = slut[u.x & 15] * sc;
      w[p][1] = slut[(u.x >> 4) & 15] * sc;
      w[p][2] = slut[u.y & 15] * sc;
      w[p][3] = slut[(u.y >> 4) & 15] * sc;
      w[p][4] = slut[u.z & 15] * sc;
      w[p][5] = slut[(u.z >> 4) & 15] * sc;
      w[p][6] = slut[u.w & 15] * sc;
      w[p][7] = slut[(u.w >> 4) & 15] * sc;
    }
    #pragma unroll 2
    for (int r = 0; r < 16; ++r) {
      const float* ar = lA + (size_t)r * IN_F + ib;
      const float4 a0 = *(const float4*)(ar);
      const float4 a1 = *(const float4*)(ar + 4);
      float b[8];
      #pragma unroll
      for (int p = 0; p < 8; ++p) b[p] = lB[(size_t)(o0 + p) * RANK + r];
      #pragma unroll
      for (int p = 0; p < 8; ++p) {
        w[p][0] += b[p] * a0.x; w[p][1] += b[p] * a0.y;
        w[p][2] += b[p] * a0.z; w[p][3] += b[p] * a0.w;
        w[p][4] += b[p] * a1.x; w[p][5] += b[p] * a1.y;
        w[p][6] += b[p] * a1.z; w[p][7] += b[p] * a1.w;
      }
    }
    #pragma unroll
    for (int p = 0; p < 8; ++p) {
      short8 s;
      #pragma unroll
      for (int qq = 0; qq < 8; ++qq) s[qq] = f2bf(w[p][qq]);
      *(short8*)&W[(size_t)(o0 + p) * IN_F + ib] = s;
    }
  }
}

// ---------------------------------------------------------------------------
// Kernel 2: x fp32 -> bf16
// ---------------------------------------------------------------------------
__global__ __launch_bounds__(256) void cvt_x_kernel(
    const float* __restrict__ x, __hip_bfloat16* __restrict__ xb) {
  constexpr int NG = (M_ROWS * IN_F) / 8;
  const int stride = gridDim.x * blockDim.x;
  for (int i = blockIdx.x * blockDim.x + threadIdx.x; i < NG; i += stride) {
    const float4 a = ((const float4*)x)[2 * i];
    const float4 b = ((const float4*)x)[2 * i + 1];
    short8 s;
    s[0] = f2bf(a.x); s[1] = f2bf(a.y); s[2] = f2bf(a.z); s[3] = f2bf(a.w);
    s[4] = f2bf(b.x); s[5] = f2bf(b.y); s[6] = f2bf(b.z); s[7] = f2bf(b.w);
    ((short8*)xb)[i] = s;
  }
}

// ---------------------------------------------------------------------------
// Kernel 3: 256x256-tile bf16 MFMA GEMM, OCCUPANCY-FIRST variant:
//   64 KiB LDS (BK=32, 2-deep double buffer) -> 2 blocks/CU co-resident.
//   Cross-block overlap (m114 mechanism) fills each block's barrier/LDS
//   stalls with the other block's MFMAs — the lever every 128-KiB variant
//   (R3-R6, all ~283-304 us regardless of schedule) was missing.
// Per K-tile: [stage(t+1) -> 4 gload_lds; vmcnt(4) (drains tile t exactly);
//   barrier; 12 ds_read_b128; setprio(1); 32 MFMA; setprio(0); barrier].
// C[M][N] = A[M][K]*B[N][K]^T + bias. 512 thr = 8 waves (2Mx4N), per-wave
// 128x64 out. LDS [2][256][32] per operand, slot-XOR swizzle
// (row,sp)->(row, sp^((row>>1)&3)): linear gload dest + pre-swizzled global
// source + same XOR on ds_read (R3-verified: 0 bank conflicts).
// ---------------------------------------------------------------------------
constexpr int BM = 256, BN = 256, BK = 32;
constexpr int GM = M_ROWS, GN = OUT_F, GK = IN_F;
constexpr int NKT = GK / BK;  // 128

#define TILE(BUF, T)                                                       \
  do {                                                                     \
    const int tn_ = ((T) + 1 < NKT) ? (T) + 1 : (T);                       \
    stage(Abase + (size_t)tn_ * BK, &sA[(BUF) ^ 1][0][0]);                 \
    stage(Bbase + (size_t)tn_ * BK, &sB[(BUF) ^ 1][0][0]);                 \
    asm volatile("s_waitcnt vmcnt(4)" ::: "memory");                       \
    __builtin_amdgcn_s_barrier();                                          \
    short8 af[8], bf[4];                                                   \
    _Pragma("unroll")                                                      \
    for (int n_ = 0; n_ < 4; ++n_)                                         \
      bf[n_] = *(const short8*)&sB[BUF][wn * 64 + n_ * 16 + lr][swr * 8];  \
    _Pragma("unroll")                                                      \
    for (int m_ = 0; m_ < 8; ++m_)                                         \
      af[m_] = *(const short8*)&sA[BUF][wm * 128 + m_ * 16 + lr][swr * 8]; \
    __builtin_amdgcn_s_setprio(1);                                         \
    _Pragma("unroll")                                                      \
    for (int m_ = 0; m_ < 8; ++m_)                                         \
      _Pragma("unroll")                                                    \
      for (int n_ = 0; n_ < 4; ++n_)                                       \
        acc[m_][n_] = __builtin_amdgcn_mfma_f32_16x16x32_bf16(             \
            af[m_], bf[n_], acc[m_][n_], 0, 0, 0);                         \
    __builtin_amdgcn_s_setprio(0);                                         \
    __builtin_amdgcn_sched_barrier(0);                                     \
    __builtin_amdgcn_s_barrier();                                          \
  } while (0)

__global__ __launch_bounds__(512, 4) void gemm_bt_db(
    const __hip_bfloat16* __restrict__ A,  // [M][K] bf16
    const __hip_bfloat16* __restrict__ B,  // [N][K] bf16
    const float* __restrict__ bias,        // [N]
    float* __restrict__ C) {               // [M][N] fp32
  __shared__ __hip_bfloat16 sA[2][256][32];  // 32 KiB
  __shared__ __hip_bfloat16 sB[2][256][32];  // 32 KiB

  const int tid  = threadIdx.x;
  const int lane = tid & 63;
  const int wave = tid >> 6;
  const int lr = lane & 15;
  const int lk = lane >> 4;
  const int wm = wave >> 2;   // 0..1
  const int wn = wave & 3;    // 0..3
  // swizzled read slot: fragment rows differ from lr by multiples of 16,
  // so (row>>1)&3 == (lr>>1)&3 -> per-lane constant
  const int swr = lk ^ ((lr >> 1) & 3);

  // T1: XCD-aware swizzle (nwg=512, %8==0 -> bijective)
  const int bid = blockIdx.x;
  const int cpx = gridDim.x >> 3;
  const int wg  = (bid & 7) * cpx + (bid >> 3);
  const int nbn = GN / BN;    // 16
  const int m0 = (wg / nbn) * BM;
  const int n0 = (wg % nbn) * BN;

  const __hip_bfloat16* Abase = A + (size_t)m0 * GK;
  const __hip_bfloat16* Bbase = B + (size_t)n0 * GK;

  // stage one 256x32 tile (16 KiB): 1024 granules, 2 gload16/thread.
  // Physical granule (row=c>>2, sp=c&3) receives global slot sp ^ ((row>>1)&3).
  const int swst = (tid >> 3) & 3;
  auto stage = [&](const __hip_bfloat16* gb, __hip_bfloat16* lb) {
    #pragma unroll
    for (int j = 0; j < 2; ++j) {
      const int c = j * 512 + tid;
      const int row = c >> 2, slot = c & 3;
      const int sg = slot ^ swst;
      gload16(gb + (size_t)row * GK + sg * 8,
              (void*)((char*)lb + (j * 512 + wave * 64) * 16));
    }
  };

  f32x4 acc[8][4];
  #pragma unroll
  for (int m = 0; m < 8; ++m)
    #pragma unroll
    for (int n = 0; n < 4; ++n) acc[m][n] = (f32x4)0.0f;

  // Prologue: stage tile 0 (4 VMEM instr outstanding).
  stage(Abase, &sA[0][0][0]);
  stage(Bbase, &sB[0][0][0]);

  // Each TILE: +4 issued -> 8 outstanding; vmcnt(4) drains exactly the
  // previous tile's 4. Tail clamp stages tile-t data into the unread buffer.
  for (int t = 0; t < NKT; t += 2) {
    TILE(0, t);
    TILE(1, t + 1);
  }

  // epilogue: C = acc + bias
  #pragma unroll
  for (int n = 0; n < 4; ++n) {
    const int col = n0 + wn * 64 + n * 16 + lr;
    const float bv = bias[col];
    #pragma unroll
    for (int m = 0; m < 8; ++m) {
      const int row = m0 + wm * 128 + m * 16 + lk * 4;
      #pragma unroll
      for (int j = 0; j < 4; ++j)
        C[(size_t)(row + j) * GN + col] = acc[m][n][j] + bv;
    }
  }
}

// ---------------------------------------------------------------------------
extern "C" void kernel_launch(void* const* d_in, const int* in_sizes, int n_in,
                              void* d_out, int out_size, void* d_ws, size_t ws_size,
                              hipStream_t stream) {
  const float* x    = (const float*)d_in[0];
  const int*   qw   = (const int*)d_in[1];
  const float* wmax = (const float*)d_in[2];
  const float* lut  = (const float*)d_in[3];
  const float* lA   = (const float*)d_in[4];
  const float* lB   = (const float*)d_in[5];
  const float* bias = (const float*)d_in[6];
  float* out = (float*)d_out;

  __hip_bfloat16* Weff = (__hip_bfloat16*)d_ws;                       // 33.5 MB
  __hip_bfloat16* xb   = (__hip_bfloat16*)((char*)d_ws + (size_t)OUT_F * IN_F * 2); // 67 MB

  dequant_lora_kernel<<<dim3(IN_F / 512, OUT_F / 64), 256, 0, stream>>>(
      qw, wmax, lut, lA, lB, Weff);
  cvt_x_kernel<<<2048, 256, 0, stream>>>(x, xb);
  gemm_bt_db<<<(GM / BM) * (GN / BN), 512, 0, stream>>>(xb, Weff, bias, out);
}

// Round 8
// 403.497 us; speedup vs baseline: 7.5454x; 7.5454x over previous
//
#include <hip/hip_runtime.h>
#include <hip/hip_bf16.h>
#include <stdint.h>

// Problem constants
constexpr int IN_F  = 4096;
constexpr int OUT_F = 4096;
constexpr int M_ROWS = 4 * 2048;   // 8192
constexpr int RANK = 16;

typedef short short8 __attribute__((ext_vector_type(8)));
typedef float f32x4 __attribute__((ext_vector_type(4)));

__device__ __forceinline__ short f2bf(float f) {
  return __builtin_bit_cast(short, __float2bfloat16(f));
}

__device__ __forceinline__ void gload16(const void* g, void* l) {
  __builtin_amdgcn_global_load_lds(
      (const __attribute__((address_space(1))) void*)g,
      (__attribute__((address_space(3))) void*)l, 16, 0, 0);
}

// ---------------------------------------------------------------------------
// Kernel 1: dequantize 4-bit weights, fold rank-16 LoRA update, emit bf16 W_eff
// ---------------------------------------------------------------------------
__global__ __launch_bounds__(256) void dequant_lora_kernel(
    const int* __restrict__ q,        // packed bytes, one byte per int32
    const float* __restrict__ wmax,
    const float* __restrict__ lut,
    const float* __restrict__ lA,     // [RANK][IN_F]
    const float* __restrict__ lB,     // [OUT_F][RANK]
    __hip_bfloat16* __restrict__ W) { // [OUT_F][IN_F]
  __shared__ float slut[16];
  if (threadIdx.x < 16) slut[threadIdx.x] = lut[threadIdx.x];
  __syncthreads();

  const int o0  = blockIdx.y * 64 + (threadIdx.x >> 5) * 8;   // 8 rows per thread
  const int ib0 = blockIdx.x * 512 + (threadIdx.x & 31) * 16; // 16 cols per thread

  #pragma unroll
  for (int h = 0; h < 2; ++h) {
    const int ib = ib0 + h * 8;
    float w[8][8];
    #pragma unroll
    for (int p = 0; p < 8; ++p) {
      const size_t l = (size_t)(o0 + p) * IN_F + ib;
      const int4 u = *(const int4*)(q + (l >> 1));   // 4 bytes -> 8 nibbles
      const float sc = wmax[l >> 6];
      w[p][0] = slut[u.x & 15] * sc;
      w[p][1] = slut[(u.x >> 4) & 15] * sc;
      w[p][2] = slut[u.y & 15] * sc;
      w[p][3] = slut[(u.y >> 4) & 15] * sc;
      w[p][4] = slut[u.z & 15] * sc;
      w[p][5] = slut[(u.z >> 4) & 15] * sc;
      w[p][6] = slut[u.w & 15] * sc;
      w[p][7] = slut[(u.w >> 4) & 15] * sc;
    }
    #pragma unroll 2
    for (int r = 0; r < 16; ++r) {
      const float* ar = lA + (size_t)r * IN_F + ib;
      const float4 a0 = *(const float4*)(ar);
      const float4 a1 = *(const float4*)(ar + 4);
      float b[8];
      #pragma unroll
      for (int p = 0; p < 8; ++p) b[p] = lB[(size_t)(o0 + p) * RANK + r];
      #pragma unroll
      for (int p = 0; p < 8; ++p) {
        w[p][0] += b[p] * a0.x; w[p][1] += b[p] * a0.y;
        w[p][2] += b[p] * a0.z; w[p][3] += b[p] * a0.w;
        w[p][4] += b[p] * a1.x; w[p][5] += b[p] * a1.y;
        w[p][6] += b[p] * a1.z; w[p][7] += b[p] * a1.w;
      }
    }
    #pragma unroll
    for (int p = 0; p < 8; ++p) {
      short8 s;
      #pragma unroll
      for (int qq = 0; qq < 8; ++qq) s[qq] = f2bf(w[p][qq]);
      *(short8*)&W[(size_t)(o0 + p) * IN_F + ib] = s;
    }
  }
}

// ---------------------------------------------------------------------------
// Kernel 2: x fp32 -> bf16
// ---------------------------------------------------------------------------
__global__ __launch_bounds__(256) void cvt_x_kernel(
    const float* __restrict__ x, __hip_bfloat16* __restrict__ xb) {
  constexpr int NG = (M_ROWS * IN_F) / 8;
  const int stride = gridDim.x * blockDim.x;
  for (int i = blockIdx.x * blockDim.x + threadIdx.x; i < NG; i += stride) {
    const float4 a = ((const float4*)x)[2 * i];
    const float4 b = ((const float4*)x)[2 * i + 1];
    short8 s;
    s[0] = f2bf(a.x); s[1] = f2bf(a.y); s[2] = f2bf(a.z); s[3] = f2bf(a.w);
    s[4] = f2bf(b.x); s[5] = f2bf(b.y); s[6] = f2bf(b.z); s[7] = f2bf(b.w);
    ((short8*)xb)[i] = s;
  }
}

// ---------------------------------------------------------------------------
// Kernel 3: 128x128-tile bf16 MFMA GEMM — OCCUPANCY-FIRST, spill-safe:
//   4 waves (256 thr), per-wave 64x64 output -> acc[4][4] = 64 VGPR (fits the
//   128-VGPR cap that 4 waves/SIMD requires; R7's 128-VGPR acc could not).
//   BK=32 double-buffer -> 32 KiB LDS -> 4 blocks/CU = 16 waves/CU.
//   Co-resident independent blocks at different phases overlap MFMA with the
//   other blocks' LDS/stage/barrier time (m114) — the lever R3-R6's
//   1-block/CU 128-KiB variants (all 283-304 us) structurally lacked.
// Per K-tile: [stage(t+1) -> 4 gload_lds; vmcnt(4) (drains tile t exactly);
//   barrier; 8 ds_read_b128; setprio(1); 16 MFMA; setprio(0); barrier].
// LDS [2][128][32] per operand, slot-XOR swizzle (row,sp)->(row,sp^((row>>1)&3)):
// linear gload dest + pre-swizzled global source + same XOR on ds_read
// (R3-verified: 0 bank conflicts).
// ---------------------------------------------------------------------------
constexpr int BM = 128, BN = 128, BK = 32;
constexpr int GM = M_ROWS, GN = OUT_F, GK = IN_F;
constexpr int NKT = GK / BK;  // 128

#define TILE(BUF, T)                                                       \
  do {                                                                     \
    const int tn_ = ((T) + 1 < NKT) ? (T) + 1 : (T);                       \
    const __hip_bfloat16* ga_ = Abase + (size_t)tn_ * BK;                  \
    const __hip_bfloat16* gb_ = Bbase + (size_t)tn_ * BK;                  \
    gload16(ga_ + sro0, (char*)&sA[(BUF) ^ 1][0][0] + lwo0);               \
    gload16(ga_ + sro1, (char*)&sA[(BUF) ^ 1][0][0] + lwo1);               \
    gload16(gb_ + sro0, (char*)&sB[(BUF) ^ 1][0][0] + lwo0);               \
    gload16(gb_ + sro1, (char*)&sB[(BUF) ^ 1][0][0] + lwo1);               \
    asm volatile("s_waitcnt vmcnt(4)" ::: "memory");                       \
    __builtin_amdgcn_s_barrier();                                          \
    short8 af[4], bf[4];                                                   \
    _Pragma("unroll")                                                      \
    for (int n_ = 0; n_ < 4; ++n_)                                         \
      bf[n_] = *(const short8*)&sB[BUF][wn * 64 + n_ * 16 + lr][swr * 8];  \
    _Pragma("unroll")                                                      \
    for (int m_ = 0; m_ < 4; ++m_)                                         \
      af[m_] = *(const short8*)&sA[BUF][wm * 64 + m_ * 16 + lr][swr * 8];  \
    __builtin_amdgcn_s_setprio(1);                                         \
    _Pragma("unroll")                                                      \
    for (int m_ = 0; m_ < 4; ++m_)                                         \
      _Pragma("unroll")                                                    \
      for (int n_ = 0; n_ < 4; ++n_)                                       \
        acc[m_][n_] = __builtin_amdgcn_mfma_f32_16x16x32_bf16(             \
            af[m_], bf[n_], acc[m_][n_], 0, 0, 0);                         \
    __builtin_amdgcn_s_setprio(0);                                         \
    __builtin_amdgcn_sched_barrier(0);                                     \
    __builtin_amdgcn_s_barrier();                                          \
  } while (0)

__global__ __launch_bounds__(256, 4) void gemm_bt_occ(
    const __hip_bfloat16* __restrict__ A,  // [M][K] bf16
    const __hip_bfloat16* __restrict__ B,  // [N][K] bf16
    const float* __restrict__ bias,        // [N]
    float* __restrict__ C) {               // [M][N] fp32
  __shared__ __hip_bfloat16 sA[2][128][32];  // 16 KiB
  __shared__ __hip_bfloat16 sB[2][128][32];  // 16 KiB

  const int tid  = threadIdx.x;
  const int lane = tid & 63;
  const int wave = tid >> 6;    // 0..3
  const int lr = lane & 15;
  const int lk = lane >> 4;
  const int wm = wave >> 1;     // 0..1
  const int wn = wave & 1;      // 0..1
  // swizzled read slot: fragment rows differ from lr by multiples of 16,
  // so (row>>1)&3 == (lr>>1)&3 -> per-lane constant
  const int swr = lk ^ ((lr >> 1) & 3);

  // T1: XCD-aware swizzle (nwg=2048, %8==0 -> bijective)
  const int bid = blockIdx.x;
  const int cpx = gridDim.x >> 3;
  const int wg  = (bid & 7) * cpx + (bid >> 3);
  const int nbn = GN / BN;      // 32
  const int m0 = (wg / nbn) * BM;
  const int n0 = (wg % nbn) * BN;

  const __hip_bfloat16* Abase = A + (size_t)m0 * GK;
  const __hip_bfloat16* Bbase = B + (size_t)n0 * GK;

  // Staging precompute: one 128x32 tile (8 KiB) = 512 granules, 2/thread.
  // Physical granule (row=c>>2, sp=c&3) receives global slot sp^((row>>1)&3);
  // swst = (c>>3)&3 = (tid>>3)&3 for both j (256 = 0 mod 32).
  const int swst = (tid >> 3) & 3;
  const int c0 = tid, c1 = 256 + tid;
  const size_t sro0 = (size_t)(c0 >> 2) * GK + (size_t)(((c0 & 3) ^ swst) * 8);
  const size_t sro1 = (size_t)(c1 >> 2) * GK + (size_t)(((c1 & 3) ^ swst) * 8);
  const int lwo0 = (wave * 64) * 16;          // wave-uniform LDS chunk base
  const int lwo1 = (256 + wave * 64) * 16;

  f32x4 acc[4][4];
  #pragma unroll
  for (int m = 0; m < 4; ++m)
    #pragma unroll
    for (int n = 0; n < 4; ++n) acc[m][n] = (f32x4)0.0f;

  // Prologue: stage tile 0 (4 VMEM instr outstanding).
  gload16(Abase + sro0, (char*)&sA[0][0][0] + lwo0);
  gload16(Abase + sro1, (char*)&sA[0][0][0] + lwo1);
  gload16(Bbase + sro0, (char*)&sB[0][0][0] + lwo0);
  gload16(Bbase + sro1, (char*)&sB[0][0][0] + lwo1);

  // Each TILE: +4 issued -> 8 outstanding; vmcnt(4) drains exactly the
  // previous tile's 4. Tail clamp restages tile-t data into the unread buffer.
  for (int t = 0; t < NKT; t += 2) {
    TILE(0, t);
    TILE(1, t + 1);
  }

  // epilogue: C = acc + bias
  #pragma unroll
  for (int n = 0; n < 4; ++n) {
    const int col = n0 + wn * 64 + n * 16 + lr;
    const float bv = bias[col];
    #pragma unroll
    for (int m = 0; m < 4; ++m) {
      const int row = m0 + wm * 64 + m * 16 + lk * 4;
      #pragma unroll
      for (int j = 0; j < 4; ++j)
        C[(size_t)(row + j) * GN + col] = acc[m][n][j] + bv;
    }
  }
}

// ---------------------------------------------------------------------------
extern "C" void kernel_launch(void* const* d_in, const int* in_sizes, int n_in,
                              void* d_out, int out_size, void* d_ws, size_t ws_size,
                              hipStream_t stream) {
  const float* x    = (const float*)d_in[0];
  const int*   qw   = (const int*)d_in[1];
  const float* wmax = (const float*)d_in[2];
  const float* lut  = (const float*)d_in[3];
  const float* lA   = (const float*)d_in[4];
  const float* lB   = (const float*)d_in[5];
  const float* bias = (const float*)d_in[6];
  float* out = (float*)d_out;

  __hip_bfloat16* Weff = (__hip_bfloat16*)d_ws;                       // 33.5 MB
  __hip_bfloat16* xb   = (__hip_bfloat16*)((char*)d_ws + (size_t)OUT_F * IN_F * 2); // 67 MB

  dequant_lora_kernel<<<dim3(IN_F / 512, OUT_F / 64), 256, 0, stream>>>(
      qw, wmax, lut, lA, lB, Weff);
  cvt_x_kernel<<<2048, 256, 0, stream>>>(x, xb);
  gemm_bt_occ<<<(GM / BM) * (GN / BN), 256, 0, stream>>>(xb, Weff, bias, out);
}

// Round 9
// 323.424 us; speedup vs baseline: 9.4135x; 1.2476x over previous
//
#include <hip/hip_runtime.h>
#include <hip/hip_bf16.h>
#include <stdint.h>

// Problem constants
constexpr int IN_F  = 4096;
constexpr int OUT_F = 4096;
constexpr int M_ROWS = 4 * 2048;   // 8192
constexpr int RANK = 16;

typedef short short8 __attribute__((ext_vector_type(8)));
typedef float f32x4 __attribute__((ext_vector_type(4)));

__device__ __forceinline__ short f2bf(float f) {
  return __builtin_bit_cast(short, __float2bfloat16(f));
}

__device__ __forceinline__ void gload16(const void* g, void* l) {
  __builtin_amdgcn_global_load_lds(
      (const __attribute__((address_space(1))) void*)g,
      (__attribute__((address_space(3))) void*)l, 16, 0, 0);
}

// ---------------------------------------------------------------------------
// Kernel 1 (fused): blocks 0..511 dequantize+LoRA-fold W_eff; blocks 512..2559
// convert x fp32->bf16.  Both roles are HBM-bound; fusing overlaps their
// bandwidth windows instead of serializing two dispatches (~45us -> ~33us).
// ---------------------------------------------------------------------------
__global__ __launch_bounds__(256) void prep_kernel(
    const int* __restrict__ q,        // packed bytes, one byte per int32
    const float* __restrict__ wmax,
    const float* __restrict__ lut,
    const float* __restrict__ lA,     // [RANK][IN_F]
    const float* __restrict__ lB,     // [OUT_F][RANK]
    const float* __restrict__ x,
    __hip_bfloat16* __restrict__ W,   // [OUT_F][IN_F]
    __hip_bfloat16* __restrict__ xb) {
  if (blockIdx.x < 512) {
    // ---- dequant + LoRA role ----
    __shared__ float slut[16];
    if (threadIdx.x < 16) slut[threadIdx.x] = lut[threadIdx.x];
    __syncthreads();

    const int bx = blockIdx.x & 7, by = blockIdx.x >> 3;
    const int o0  = by * 64 + (threadIdx.x >> 5) * 8;
    const int ib0 = bx * 512 + (threadIdx.x & 31) * 16;

    #pragma unroll
    for (int h = 0; h < 2; ++h) {
      const int ib = ib0 + h * 8;
      float w[8][8];
      #pragma unroll
      for (int p = 0; p < 8; ++p) {
        const size_t l = (size_t)(o0 + p) * IN_F + ib;
        const int4 u = *(const int4*)(q + (l >> 1));
        const float sc = wmax[l >> 6];
        w[p][0] = slut[u.x & 15] * sc;
        w[p][1] = slut[(u.x >> 4) & 15] * sc;
        w[p][2] = slut[u.y & 15] * sc;
        w[p][3] = slut[(u.y >> 4) & 15] * sc;
        w[p][4] = slut[u.z & 15] * sc;
        w[p][5] = slut[(u.z >> 4) & 15] * sc;
        w[p][6] = slut[u.w & 15] * sc;
        w[p][7] = slut[(u.w >> 4) & 15] * sc;
      }
      #pragma unroll 2
      for (int r = 0; r < 16; ++r) {
        const float* ar = lA + (size_t)r * IN_F + ib;
        const float4 a0 = *(const float4*)(ar);
        const float4 a1 = *(const float4*)(ar + 4);
        float b[8];
        #pragma unroll
        for (int p = 0; p < 8; ++p) b[p] = lB[(size_t)(o0 + p) * RANK + r];
        #pragma unroll
        for (int p = 0; p < 8; ++p) {
          w[p][0] += b[p] * a0.x; w[p][1] += b[p] * a0.y;
          w[p][2] += b[p] * a0.z; w[p][3] += b[p] * a0.w;
          w[p][4] += b[p] * a1.x; w[p][5] += b[p] * a1.y;
          w[p][6] += b[p] * a1.z; w[p][7] += b[p] * a1.w;
        }
      }
      #pragma unroll
      for (int p = 0; p < 8; ++p) {
        short8 s;
        #pragma unroll
        for (int qq = 0; qq < 8; ++qq) s[qq] = f2bf(w[p][qq]);
        *(short8*)&W[(size_t)(o0 + p) * IN_F + ib] = s;
      }
    }
  } else {
    // ---- x fp32 -> bf16 role ----
    constexpr int NG = (M_ROWS * IN_F) / 8;
    const int nblk = 2048;
    const int stride = nblk * 256;
    for (int i = (blockIdx.x - 512) * 256 + threadIdx.x; i < NG; i += stride) {
      const float4 a = ((const float4*)x)[2 * i];
      const float4 b = ((const float4*)x)[2 * i + 1];
      short8 s;
      s[0] = f2bf(a.x); s[1] = f2bf(a.y); s[2] = f2bf(a.z); s[3] = f2bf(a.w);
      s[4] = f2bf(b.x); s[5] = f2bf(b.y); s[6] = f2bf(b.z); s[7] = f2bf(b.w);
      ((short8*)xb)[i] = s;
    }
  }
}

// ---------------------------------------------------------------------------
// Kernel 2: 256x256-tile 8-phase bf16 MFMA GEMM — SINGLE-BARRIER phases.
// R9 change vs R3/R5 (both 283us, MfmaUtil 43.5): one block-wide barrier per
// phase instead of two.  New phase order: [vm@p4,p8; BAR; stage; reads; MFMA].
// Safety (audited per region): reads of phase p are consumed by phase p's own
// MFMA (compiler lgkm wait) before the wave reaches bar(p+1); any re-stage of
// that region happens after a later barrier => >=1 full barrier between
// last-read and overwrite.  Staged regions are published by vmcnt(6)@p4/p8 +
// barrier >= 4 phases before first read (ledger re-verified for stage-after-
// barrier order).  Everything else identical to R3: [256][32] K-half regions,
// slot-XOR swizzle (0 conflicts measured), gload_lds width-16, XCD swizzle,
// setprio around 16-MFMA clusters, vmcnt never drained to 0.
// ---------------------------------------------------------------------------
constexpr int BM = 256, BN = 256, BK = 64;
constexpr int GM = M_ROWS, GN = OUT_F, GK = IN_F;
constexpr int NKT = GK / BK;  // 64

#define LOAD_B(BUF, KH)                                                   \
  _Pragma("unroll")                                                       \
  for (int n_ = 0; n_ < 4; ++n_)                                          \
    bf[n_] = *(const short8*)&sB[BUF][KH][wn * 64 + n_ * 16 + lr][swr * 8];

#define LOAD_A(BUF, KH, MH)                                               \
  _Pragma("unroll")                                                       \
  for (int i_ = 0; i_ < 4; ++i_)                                          \
    af[i_] = *(const short8*)&sA[BUF][KH][wm * 128 + (MH) * 64 + i_ * 16 + lr][swr * 8];

#define MFMA_Q(MH)                                                        \
  __builtin_amdgcn_s_setprio(1);                                          \
  _Pragma("unroll")                                                       \
  for (int i_ = 0; i_ < 4; ++i_)                                          \
    _Pragma("unroll")                                                     \
    for (int n_ = 0; n_ < 4; ++n_)                                        \
      acc[(MH) * 4 + i_][n_] = __builtin_amdgcn_mfma_f32_16x16x32_bf16(   \
          af[i_], bf[n_], acc[(MH) * 4 + i_][n_], 0, 0, 0);               \
  __builtin_amdgcn_s_setprio(0);

#define PHASE(BUF, KH, MH, DOB, GB, LB, VM)                               \
  do {                                                                    \
    if (VM) asm volatile("s_waitcnt vmcnt(6)" ::: "memory");              \
    __builtin_amdgcn_s_barrier();                                         \
    stage(GB, LB);                                                        \
    if (DOB) { LOAD_B(BUF, KH) }                                          \
    LOAD_A(BUF, KH, MH)                                                   \
    MFMA_Q(MH)                                                            \
    __builtin_amdgcn_sched_barrier(0);                                    \
  } while (0)

__global__ __launch_bounds__(512, 2) void gemm_bt_1bar(
    const __hip_bfloat16* __restrict__ A,  // [M][K] bf16
    const __hip_bfloat16* __restrict__ B,  // [N][K] bf16
    const float* __restrict__ bias,        // [N]
    float* __restrict__ C) {               // [M][N] fp32
  __shared__ __hip_bfloat16 sA[2][2][256][32];  // 64 KiB
  __shared__ __hip_bfloat16 sB[2][2][256][32];  // 64 KiB

  const int tid  = threadIdx.x;
  const int lane = tid & 63;
  const int wave = tid >> 6;
  const int lr = lane & 15;
  const int lk = lane >> 4;
  const int wm = wave >> 2;   // 0..1
  const int wn = wave & 3;    // 0..3
  // swizzled read slot: fragment rows differ from lr by multiples of 16,
  // so (row>>1)&3 == (lr>>1)&3 -> per-lane constant
  const int swr = lk ^ ((lr >> 1) & 3);

  // T1: XCD-aware swizzle (nwg=512, %8==0 -> bijective)
  const int bid = blockIdx.x;
  const int cpx = gridDim.x >> 3;
  const int wg  = (bid & 7) * cpx + (bid >> 3);
  const int nbn = GN / BN;    // 16
  const int m0 = (wg / nbn) * BM;
  const int n0 = (wg % nbn) * BN;

  const __hip_bfloat16* Abase = A + (size_t)m0 * GK;
  const __hip_bfloat16* Bbase = B + (size_t)n0 * GK;

  // stage one 256x32 K-half region (16 KiB): 1024 granules, 2 gload16/thread.
  // Physical granule (row=c>>2, sp=c&3) receives global slot sp ^ ((row>>1)&3).
  const int swst = (tid >> 3) & 3;
  auto stage = [&](const __hip_bfloat16* gb, __hip_bfloat16* lb) {
    #pragma unroll
    for (int j = 0; j < 2; ++j) {
      const int c = j * 512 + tid;
      const int row = c >> 2, slot = c & 3;
      const int sg = slot ^ swst;
      gload16(gb + (size_t)row * GK + sg * 8,
              (void*)((char*)lb + (j * 512 + wave * 64) * 16));
    }
  };

  f32x4 acc[8][4];
  #pragma unroll
  for (int m = 0; m < 8; ++m)
    #pragma unroll
    for (int n = 0; n < 4; ++n) acc[m][n] = (f32x4)0.0f;

  // Prologue: tile0 fully + tile1 {Bk0, Ak0, Bk1} = 14 VMEM instr;
  // vmcnt(6) -> stages 1-4 (sA00,sB00,sA01,sB01) complete before phase-1's
  // barrier publishes them.
  stage(Abase +  0, &sA[0][0][0][0]);
  stage(Bbase +  0, &sB[0][0][0][0]);
  stage(Abase + 32, &sA[0][1][0][0]);
  stage(Bbase + 32, &sB[0][1][0][0]);
  stage(Bbase + 64, &sB[1][0][0][0]);
  stage(Abase + 64, &sA[1][0][0][0]);
  stage(Bbase + 96, &sB[1][1][0][0]);
  asm volatile("s_waitcnt vmcnt(6)" ::: "memory");

  short8 af[4], bf[4];

  for (int t = 0; t < NKT; t += 2) {
    // clamp keeps vmcnt counting exact on the last iterations; clamped
    // stages land only in regions that are never read again.
    const int t2 = (t + 2 < NKT) ? t + 2 : NKT - 1;
    const int t3 = (t + 3 < NKT) ? t + 3 : NKT - 1;

    PHASE(0, 0, 0, true,  Abase + (size_t)(t + 1) * 64 + 32, &sA[1][1][0][0], false);
    PHASE(0, 0, 1, false, Bbase + (size_t)t2 * 64,           &sB[0][0][0][0], false);
    PHASE(0, 1, 0, true,  Abase + (size_t)t2 * 64,           &sA[0][0][0][0], false);
    PHASE(0, 1, 1, false, Bbase + (size_t)t2 * 64 + 32,      &sB[0][1][0][0], true);
    PHASE(1, 0, 0, true,  Abase + (size_t)t2 * 64 + 32,      &sA[0][1][0][0], false);
    PHASE(1, 0, 1, false, Bbase + (size_t)t3 * 64,           &sB[1][0][0][0], false);
    PHASE(1, 1, 0, true,  Abase + (size_t)t3 * 64,           &sA[1][0][0][0], false);
    PHASE(1, 1, 1, false, Bbase + (size_t)t3 * 64 + 32,      &sB[1][1][0][0], true);
  }

  // epilogue: C = acc + bias
  #pragma unroll
  for (int n = 0; n < 4; ++n) {
    const int col = n0 + wn * 64 + n * 16 + lr;
    const float bv = bias[col];
    #pragma unroll
    for (int m = 0; m < 8; ++m) {
      const int row = m0 + wm * 128 + m * 16 + lk * 4;
      #pragma unroll
      for (int j = 0; j < 4; ++j)
        C[(size_t)(row + j) * GN + col] = acc[m][n][j] + bv;
    }
  }
}

// ---------------------------------------------------------------------------
extern "C" void kernel_launch(void* const* d_in, const int* in_sizes, int n_in,
                              void* d_out, int out_size, void* d_ws, size_t ws_size,
                              hipStream_t stream) {
  const float* x    = (const float*)d_in[0];
  const int*   qw   = (const int*)d_in[1];
  const float* wmax = (const float*)d_in[2];
  const float* lut  = (const float*)d_in[3];
  const float* lA   = (const float*)d_in[4];
  const float* lB   = (const float*)d_in[5];
  const float* bias = (const float*)d_in[6];
  float* out = (float*)d_out;

  __hip_bfloat16* Weff = (__hip_bfloat16*)d_ws;                       // 33.5 MB
  __hip_bfloat16* xb   = (__hip_bfloat16*)((char*)d_ws + (size_t)OUT_F * IN_F * 2); // 67 MB

  prep_kernel<<<2560, 256, 0, stream>>>(qw, wmax, lut, lA, lB, x, Weff, xb);
  gemm_bt_1bar<<<(GM / BM) * (GN / BN), 512, 0, stream>>>(xb, Weff, bias, out);
}